// Round 1
// baseline (183.992 us; speedup 1.0000x reference)
//
#include <hip/hip_runtime.h>

// MixtureRouting: y[b,d,m] = sum_p x[b,d,p] * coef[b,p,m]
//   lh[b,p,m]  = pi[b,m] * prod_d( sig[b,d,m] / (PI*((mu[b,d,p]-mu[b,d,m])^2 + sig[b,d,m]^2)) )
//   coef[p,m]  = lh[p,m] / sum_m lh[p,m]
// Restructure: x'[d,p] = x[d,p] / rowsum[p];  y = x' @ lh  (lh regenerated on the fly).

namespace {
constexpr int BB   = 4;
constexpr int DD   = 81;
constexpr int KK   = 2048;
constexpr int XP   = 84;              // padded row stride for x' (16B-aligned rows: 84*4=336)
constexpr int PSPLIT = 16;
constexpr int PCHUNK = KK / PSPLIT;   // 128

// ws layout in floats
constexpr size_t OFF_MUP = 0;                           // float4[B*K]  packed mu
constexpr size_t OFF_S2P = (size_t)BB * KK * 4;         // float4[B*K]  packed sig^2
constexpr size_t OFF_CC  = OFF_S2P + (size_t)BB * KK * 4; // float[B*K] c = pi*prod(sig)/PI^4
constexpr size_t OFF_IRS = OFF_CC  + (size_t)BB * KK;   // float[B*K]   1/rowsum
constexpr size_t OFF_XP  = OFF_IRS + (size_t)BB * KK;   // float[B*K*XP] x' transposed
} // namespace

__global__ void pack_kernel(const float* __restrict__ pi_in,
                            const float* __restrict__ mu,
                            const float* __restrict__ sig,
                            float4* __restrict__ mu_pack,
                            float4* __restrict__ s2_pack,
                            float* __restrict__ cc) {
    int t = blockIdx.x * blockDim.x + threadIdx.x;
    if (t >= BB * KK) return;
    int b = t >> 11;
    int k = t & (KK - 1);
    const float* mub = mu  + (size_t)b * 4 * KK + k;
    const float* sgb = sig + (size_t)b * 4 * KK + k;
    float m0 = mub[0], m1 = mub[KK], m2 = mub[2 * KK], m3 = mub[3 * KK];
    float s0 = sgb[0], s1 = sgb[KK], s2 = sgb[2 * KK], s3 = sgb[3 * KK];
    mu_pack[t] = make_float4(m0, m1, m2, m3);
    s2_pack[t] = make_float4(s0 * s0, s1 * s1, s2 * s2, s3 * s3);
    const float inv_pi4 = 1.0f / 97.40909103400243f;
    cc[t] = pi_in[(size_t)b * KK + k] * ((s0 * s1) * (s2 * s3)) * inv_pi4;
}

// one block per (b,p): rowsum over m, write 1/rowsum
__global__ __launch_bounds__(256) void rowsum_kernel(const float4* __restrict__ mu_pack,
                                                     const float4* __restrict__ s2_pack,
                                                     const float* __restrict__ cc,
                                                     float* __restrict__ invrow) {
    int bp = blockIdx.x;            // 0 .. B*K-1
    int b  = bp >> 11;
    float4 mp = mu_pack[bp];        // uniform
    float sum = 0.f;
    for (int m = threadIdx.x; m < KK; m += 256) {
        int idx = (b << 11) + m;
        float4 mm = mu_pack[idx];
        float4 s2 = s2_pack[idx];
        float d0 = mp.x - mm.x, d1 = mp.y - mm.y, d2 = mp.z - mm.z, d3 = mp.w - mm.w;
        float den = fmaf(d0, d0, s2.x) * fmaf(d1, d1, s2.y) *
                    fmaf(d2, d2, s2.z) * fmaf(d3, d3, s2.w);
        sum += cc[idx] * __builtin_amdgcn_rcpf(den);
    }
    for (int off = 32; off; off >>= 1) sum += __shfl_down(sum, off);
    __shared__ float red[4];
    int lane = threadIdx.x & 63, w = threadIdx.x >> 6;
    if (lane == 0) red[w] = sum;
    __syncthreads();
    if (threadIdx.x == 0) {
        float s = red[0] + red[1] + red[2] + red[3];
        invrow[bp] = 1.0f / s;
    }
}

// x'[b][p][d] = x[b][d][p] / rowsum[b][p]; one block of 96 threads per (b,p)
__global__ void xprime_kernel(const float* __restrict__ x,
                              const float* __restrict__ invrow,
                              float* __restrict__ xp) {
    int bp = blockIdx.x;
    int b  = bp >> 11;
    int p  = bp & (KK - 1);
    int d  = threadIdx.x;
    if (d < XP) {
        float v = 0.f;
        if (d < DD) v = x[((size_t)(b * DD + d)) * KK + p] * invrow[bp];
        xp[(size_t)bp * XP + d] = v;
    }
}

__global__ void zero_kernel(float4* __restrict__ out, int n4) {
    int i = blockIdx.x * blockDim.x + threadIdx.x;
    if (i < n4) out[i] = make_float4(0.f, 0.f, 0.f, 0.f);
}

// grid: (K/256 m-tiles, PSPLIT, B); thread owns one m-column, 81 d-accumulators
__global__ __launch_bounds__(256) void main_kernel(const float4* __restrict__ mu_pack,
                                                   const float4* __restrict__ s2_pack,
                                                   const float* __restrict__ cc,
                                                   const float* __restrict__ xp,
                                                   float* __restrict__ out) {
    int m  = blockIdx.x * 256 + threadIdx.x;
    int b  = blockIdx.z;
    int p0 = blockIdx.y * PCHUNK;
    int bm = (b << 11) + m;

    float4 mm = mu_pack[bm];
    float4 s2 = s2_pack[bm];
    float  cm = cc[bm];

    float acc[DD];
#pragma unroll
    for (int d = 0; d < DD; ++d) acc[d] = 0.f;

    for (int p = p0; p < p0 + PCHUNK; ++p) {
        int bp = (b << 11) + p;
        float4 mp = mu_pack[bp];            // uniform -> scalar load expected
        float d0 = mp.x - mm.x, d1 = mp.y - mm.y, d2 = mp.z - mm.z, d3 = mp.w - mm.w;
        float den = fmaf(d0, d0, s2.x) * fmaf(d1, d1, s2.y) *
                    fmaf(d2, d2, s2.z) * fmaf(d3, d3, s2.w);
        float lh = cm * __builtin_amdgcn_rcpf(den);
        const float* __restrict__ xr = xp + (size_t)bp * XP;   // uniform row
#pragma unroll
        for (int d = 0; d < DD; ++d) acc[d] = fmaf(xr[d], lh, acc[d]);
    }

    float* ob = out + ((size_t)b * DD) * KK + m;
#pragma unroll
    for (int d = 0; d < DD; ++d) atomicAdd(ob + (size_t)d * KK, acc[d]);
}

extern "C" void kernel_launch(void* const* d_in, const int* in_sizes, int n_in,
                              void* d_out, int out_size, void* d_ws, size_t ws_size,
                              hipStream_t stream) {
    const float* x   = (const float*)d_in[0];
    const float* pi_ = (const float*)d_in[1];
    const float* mu  = (const float*)d_in[2];
    const float* sig = (const float*)d_in[3];
    float* ws = (float*)d_ws;
    float* out = (float*)d_out;

    float4* mu_pack = (float4*)(ws + OFF_MUP);
    float4* s2_pack = (float4*)(ws + OFF_S2P);
    float*  cc      = ws + OFF_CC;
    float*  invrow  = ws + OFF_IRS;
    float*  xp      = ws + OFF_XP;

    // 1) pack per-component constants
    pack_kernel<<<(BB * KK + 255) / 256, 256, 0, stream>>>(pi_, mu, sig, mu_pack, s2_pack, cc);
    // 2) rowsums -> 1/rowsum
    rowsum_kernel<<<BB * KK, 256, 0, stream>>>(mu_pack, s2_pack, cc, invrow);
    // 3) x' = x / rowsum, transposed to [b][p][d]
    xprime_kernel<<<BB * KK, 96, 0, stream>>>(x, invrow, xp);
    // 4) zero output (harness poisons it)
    int n4 = out_size / 4;
    zero_kernel<<<(n4 + 255) / 256, 256, 0, stream>>>((float4*)out, n4);
    // 5) main contraction with on-the-fly lh regeneration + atomic partials
    dim3 grid(KK / 256, PSPLIT, BB);
    main_kernel<<<grid, 256, 0, stream>>>(mu_pack, s2_pack, cc, xp, out);
}

// Round 2
// 161.530 us; speedup vs baseline: 1.1391x; 1.1391x over previous
//
#include <hip/hip_runtime.h>

// MixtureRouting: y[b,d,m] = sum_p x[b,d,p] * coef[b,p,m]
//   lh[b,p,m]  = pi[b,m] * prod_d( sig[b,d,m] / (PI*((mu[b,d,p]-mu[b,d,m])^2 + sig[b,d,m]^2)) )
//   coef[p,m]  = lh[p,m] / sum_m lh[p,m]
// Restructure: x'[d,p] = x[d,p] / rowsum[p];  y = x' @ lh  (lh regenerated on the fly).
// R1 -> R2: fix register spill (VGPR_Count was 48 < 81 accumulators) via d-split of 2
// (44+44 padded, 11 float4 acc each) + __launch_bounds__ min-waves guard; rowsum does
// 8 p-rows per block (8x less L2 traffic); xprime coalesced via LDS transpose tile.

namespace {
constexpr int BB   = 4;
constexpr int DD   = 81;
constexpr int KK   = 2048;
constexpr int XP   = 88;              // padded row stride for x' (two halves of 44; 88*4=352B)
constexpr int PSPLIT = 16;
constexpr int PCHUNK = KK / PSPLIT;   // 128
constexpr int DSPLIT = 2;
constexpr int DHALF  = XP / DSPLIT;   // 44 = 11 float4

// ws layout in floats
constexpr size_t OFF_MUP = 0;                             // float4[B*K]  packed mu
constexpr size_t OFF_S2P = (size_t)BB * KK * 4;           // float4[B*K]  packed sig^2
constexpr size_t OFF_CC  = OFF_S2P + (size_t)BB * KK * 4; // float[B*K]   c = pi*prod(sig)/PI^4
constexpr size_t OFF_IRS = OFF_CC  + (size_t)BB * KK;     // float[B*K]   1/rowsum
constexpr size_t OFF_XP  = OFF_IRS + (size_t)BB * KK;     // float[B*K*XP] x' transposed+scaled
} // namespace

__global__ void pack_kernel(const float* __restrict__ pi_in,
                            const float* __restrict__ mu,
                            const float* __restrict__ sig,
                            float4* __restrict__ mu_pack,
                            float4* __restrict__ s2_pack,
                            float* __restrict__ cc) {
    int t = blockIdx.x * blockDim.x + threadIdx.x;
    if (t >= BB * KK) return;
    int b = t >> 11;
    int k = t & (KK - 1);
    const float* mub = mu  + (size_t)b * 4 * KK + k;
    const float* sgb = sig + (size_t)b * 4 * KK + k;
    float m0 = mub[0], m1 = mub[KK], m2 = mub[2 * KK], m3 = mub[3 * KK];
    float s0 = sgb[0], s1 = sgb[KK], s2 = sgb[2 * KK], s3 = sgb[3 * KK];
    mu_pack[t] = make_float4(m0, m1, m2, m3);
    s2_pack[t] = make_float4(s0 * s0, s1 * s1, s2 * s2, s3 * s3);
    const float inv_pi4 = 1.0f / 97.40909103400243f;
    cc[t] = pi_in[(size_t)b * KK + k] * ((s0 * s1) * (s2 * s3)) * inv_pi4;
}

// one block per 8 consecutive p: rowsum over m, write 1/rowsum. Streams the m-side
// constants (36B each) once for 8 rows -> 8x less L2 traffic than 1 row/block.
__global__ __launch_bounds__(256) void rowsum_kernel(const float4* __restrict__ mu_pack,
                                                     const float4* __restrict__ s2_pack,
                                                     const float* __restrict__ cc,
                                                     float* __restrict__ invrow) {
    constexpr int PB = 8;
    int blk  = blockIdx.x;               // 0 .. B*K/PB-1
    int b    = blk >> 8;                 // 2048/8 = 256 blocks per batch
    int p0   = (blk & 255) * PB;
    int base = b << 11;

    float4 mp[PB];
#pragma unroll
    for (int i = 0; i < PB; ++i) mp[i] = mu_pack[base + p0 + i];
    float sum[PB];
#pragma unroll
    for (int i = 0; i < PB; ++i) sum[i] = 0.f;

    for (int m = threadIdx.x; m < KK; m += 256) {
        int idx = base + m;
        float4 mm = mu_pack[idx];
        float4 s2 = s2_pack[idx];
        float  c  = cc[idx];
#pragma unroll
        for (int i = 0; i < PB; ++i) {
            float d0 = mp[i].x - mm.x, d1 = mp[i].y - mm.y;
            float d2 = mp[i].z - mm.z, d3 = mp[i].w - mm.w;
            float den = fmaf(d0, d0, s2.x) * fmaf(d1, d1, s2.y) *
                        fmaf(d2, d2, s2.z) * fmaf(d3, d3, s2.w);
            sum[i] += c * __builtin_amdgcn_rcpf(den);
        }
    }

    __shared__ float red[4][PB];
    int lane = threadIdx.x & 63, w = threadIdx.x >> 6;
#pragma unroll
    for (int i = 0; i < PB; ++i) {
        float s = sum[i];
        for (int off = 32; off; off >>= 1) s += __shfl_down(s, off);
        if (lane == 0) red[w][i] = s;
    }
    __syncthreads();
    if (threadIdx.x < PB) {
        float s = red[0][threadIdx.x] + red[1][threadIdx.x] +
                  red[2][threadIdx.x] + red[3][threadIdx.x];
        invrow[base + p0 + threadIdx.x] = 1.0f / s;
    }
}

// x'[b][p][d] = x[b][d][p] / rowsum[b][p], rows padded to XP=88 (d>=81 zero).
// 64-p LDS transpose tile so global reads are coalesced over p.
__global__ __launch_bounds__(256) void xprime_kernel(const float* __restrict__ x,
                                                     const float* __restrict__ invrow,
                                                     float* __restrict__ xp) {
    constexpr int TP = 64;
    __shared__ float tile[TP][XP + 1];   // +1 pad: stride 89 breaks bank alignment
    int b  = blockIdx.y;
    int p0 = blockIdx.x * TP;
    int pi = threadIdx.x & 63;
    int w  = threadIdx.x >> 6;           // 4 d-lanes per p

#pragma unroll
    for (int dc = 0; dc < 21; ++dc) {
        int d = dc * 4 + w;
        if (d < DD)
            tile[pi][d] = x[(((size_t)(b * DD + d)) << 11) + p0 + pi];
    }
    __syncthreads();
    float ir = invrow[(b << 11) + p0 + pi];
    float* orow = xp + ((size_t)((b << 11) + p0 + pi)) * XP;
#pragma unroll
    for (int j = 0; j < XP / 4; ++j) {   // each of 4 writers covers 22 d's
        int d = w * (XP / 4) + j;
        orow[d] = (d < DD) ? tile[pi][d] * ir : 0.f;
    }
}

__global__ void zero_kernel(float4* __restrict__ out, int n4) {
    int i = blockIdx.x * blockDim.x + threadIdx.x;
    if (i < n4) out[i] = make_float4(0.f, 0.f, 0.f, 0.f);
}

// grid: (K/256, PSPLIT, B*DSPLIT). Thread owns one m-column and one 44-d half
// (11 float4 accumulators -> fits registers; lh recomputed per half).
__global__ __launch_bounds__(256, 3) void main_kernel(const float4* __restrict__ mu_pack,
                                                      const float4* __restrict__ s2_pack,
                                                      const float* __restrict__ cc,
                                                      const float* __restrict__ xp,
                                                      float* __restrict__ out) {
    int m     = blockIdx.x * 256 + threadIdx.x;
    int zz    = blockIdx.z;
    int b     = zz >> 1;
    int dHalf = zz & 1;
    int p0    = blockIdx.y * PCHUNK;
    int bm    = (b << 11) + m;

    float4 mm = mu_pack[bm];
    float4 s2 = s2_pack[bm];
    float  cm = cc[bm];

    float4 acc[11];
#pragma unroll
    for (int j = 0; j < 11; ++j) acc[j] = make_float4(0.f, 0.f, 0.f, 0.f);

    const float4* xbase = (const float4*)xp +
                          ((size_t)((b << 11) + p0)) * (XP / 4) + dHalf * 11;

    for (int p = 0; p < PCHUNK; ++p) {
        int bp = (b << 11) + p0 + p;
        float4 mp = mu_pack[bp];                       // wave-uniform
        float d0 = mp.x - mm.x, d1 = mp.y - mm.y, d2 = mp.z - mm.z, d3 = mp.w - mm.w;
        float den = fmaf(d0, d0, s2.x) * fmaf(d1, d1, s2.y) *
                    fmaf(d2, d2, s2.z) * fmaf(d3, d3, s2.w);
        float lh = cm * __builtin_amdgcn_rcpf(den);
        const float4* __restrict__ xr = xbase + (size_t)p * (XP / 4);  // uniform row
#pragma unroll
        for (int j = 0; j < 11; ++j) {
            float4 v = xr[j];
            acc[j].x = fmaf(v.x, lh, acc[j].x);
            acc[j].y = fmaf(v.y, lh, acc[j].y);
            acc[j].z = fmaf(v.z, lh, acc[j].z);
            acc[j].w = fmaf(v.w, lh, acc[j].w);
        }
    }

    float* ob = out + ((size_t)b * DD) * KK + m;
    const float* af = (const float*)acc;
    if (dHalf == 0) {
#pragma unroll
        for (int j = 0; j < DHALF; ++j)                 // d = 0..43, all valid
            atomicAdd(ob + (size_t)j * KK, af[j]);
    } else {
#pragma unroll
        for (int j = 0; j < DHALF; ++j) {               // d = 44..87, store d<81
            int d = DHALF + j;
            if (d < DD) atomicAdd(ob + (size_t)d * KK, af[j]);
        }
    }
}

extern "C" void kernel_launch(void* const* d_in, const int* in_sizes, int n_in,
                              void* d_out, int out_size, void* d_ws, size_t ws_size,
                              hipStream_t stream) {
    const float* x   = (const float*)d_in[0];
    const float* pi_ = (const float*)d_in[1];
    const float* mu  = (const float*)d_in[2];
    const float* sig = (const float*)d_in[3];
    float* ws  = (float*)d_ws;
    float* out = (float*)d_out;

    float4* mu_pack = (float4*)(ws + OFF_MUP);
    float4* s2_pack = (float4*)(ws + OFF_S2P);
    float*  cc      = ws + OFF_CC;
    float*  invrow  = ws + OFF_IRS;
    float*  xp      = ws + OFF_XP;

    // 1) pack per-component constants
    pack_kernel<<<(BB * KK + 255) / 256, 256, 0, stream>>>(pi_, mu, sig, mu_pack, s2_pack, cc);
    // 2) rowsums -> 1/rowsum (8 rows per block)
    rowsum_kernel<<<BB * KK / 8, 256, 0, stream>>>(mu_pack, s2_pack, cc, invrow);
    // 3) x' = x / rowsum, transposed to [b][p][d] with coalesced reads
    dim3 xgrid(KK / 64, BB);
    xprime_kernel<<<xgrid, 256, 0, stream>>>(x, invrow, xp);
    // 4) zero output (harness poisons it)
    int n4 = out_size / 4;
    zero_kernel<<<(n4 + 255) / 256, 256, 0, stream>>>((float4*)out, n4);
    // 5) main contraction, lh regenerated on the fly, d split in two halves
    dim3 grid(KK / 256, PSPLIT, BB * DSPLIT);
    main_kernel<<<grid, 256, 0, stream>>>(mu_pack, s2_pack, cc, xp, out);
}